// Round 5
// baseline (824.004 us; speedup 1.0000x reference)
//
#include <hip/hip_runtime.h>
#include <stdint.h>

// ---------- types ----------
typedef short bf16x8 __attribute__((ext_vector_type(8)));
typedef float f32x4  __attribute__((ext_vector_type(4)));
typedef float f32x16 __attribute__((ext_vector_type(16)));

#define EPS_RMS 1.1920929e-07f
#define INV_SQRT_HD 0.08838834764831845f  // 1/sqrt(128)
#define NEGBIG (-3.0e38f)

// f32 -> bf16 bits, round-to-nearest-even
__device__ __forceinline__ short f2bf(float f) {
    uint32_t u = __float_as_uint(f);
    u += 0x7fffu + ((u >> 16) & 1u);
    return (short)(u >> 16);
}

__device__ __forceinline__ unsigned int pack2(float lo, float hi) {
    return (unsigned int)(unsigned short)f2bf(lo) |
           ((unsigned int)(unsigned short)f2bf(hi) << 16);
}

using gld_t = const __attribute__((address_space(1))) unsigned int*;
using lds_t = __attribute__((address_space(3))) unsigned int*;

// async global->LDS, 16 bytes per lane (lane i lands at ldsbase + i*16)
__device__ __forceinline__ void glds16(const short* g, short* l) {
    __builtin_amdgcn_global_load_lds((gld_t)g, (lds_t)l, 16, 0, 0);
}

// ---------- kernel 1: f32 -> bf16 convert (vectorized x4) ----------
__global__ void cvt_f32_bf16(const float* __restrict__ in, short* __restrict__ out, int n) {
    int i = (blockIdx.x * blockDim.x + threadIdx.x) * 4;
    int stride = gridDim.x * blockDim.x * 4;
    for (; i < n; i += stride) {
        float4 v = *(const float4*)(in + i);
        short4 o;
        o.x = f2bf(v.x); o.y = f2bf(v.y); o.z = f2bf(v.z); o.w = f2bf(v.w);
        *(short4*)(out + i) = o;
    }
}

// ---------- kernel 2: C[M,N] = A[M,K] * Bw[N,K]^T  (bf16 in, f32 out) ----------
__global__ __launch_bounds__(256, 1) void gemm_bt(
    const short* __restrict__ A, const short* __restrict__ Bw,
    float* __restrict__ C, int M, int N, int K)
{
    __shared__ short sA[128 * 32];
    __shared__ short sB[128 * 32];
    const int tid  = threadIdx.x;
    const int lane = tid & 63;
    const int wave = tid >> 6;
    const int wm = (wave >> 1) * 64;
    const int wn = (wave & 1) * 64;
    const size_t row0 = (size_t)blockIdx.y * 128;
    const size_t col0 = (size_t)blockIdx.x * 128;
    const int fr = lane & 15;
    const int fk = (lane >> 4) * 8;

    f32x4 acc[4][4] = {};

    const short* gA = A + (row0 + (tid >> 2)) * (size_t)K + (tid & 3) * 8;
    const short* gB = Bw + (col0 + (tid >> 2)) * (size_t)K + (tid & 3) * 8;
    short* lA = sA + tid * 8;
    short* lB = sB + tid * 8;

    for (int k0 = 0; k0 < K; k0 += 32) {
        glds16(gA + k0, lA);
        glds16(gA + k0 + (size_t)64 * K, lA + 2048);
        glds16(gB + k0, lB);
        glds16(gB + k0 + (size_t)64 * K, lB + 2048);
        __syncthreads();

        bf16x8 af[4], bb[4];
        #pragma unroll
        for (int m = 0; m < 4; ++m)
            af[m] = *(const bf16x8*)(sA + (wm + m * 16 + fr) * 32 + fk);
        #pragma unroll
        for (int n = 0; n < 4; ++n)
            bb[n] = *(const bf16x8*)(sB + (wn + n * 16 + fr) * 32 + fk);
        #pragma unroll
        for (int m = 0; m < 4; ++m)
            #pragma unroll
            for (int n = 0; n < 4; ++n)
                acc[m][n] = __builtin_amdgcn_mfma_f32_16x16x32_bf16(af[m], bb[n], acc[m][n], 0, 0, 0);
        __syncthreads();
    }

    const int cr = (lane >> 4) * 4;
    #pragma unroll
    for (int m = 0; m < 4; ++m)
        #pragma unroll
        for (int n = 0; n < 4; ++n)
            #pragma unroll
            for (int r = 0; r < 4; ++r)
                C[(row0 + wm + m * 16 + cr + r) * N + col0 + wn + n * 16 + fr] = acc[m][n][r];
}

// ---------- kernel 3: RoPE + RMSNorm for q,k; convert+transpose v ----------
__global__ __launch_bounds__(256, 1) void prep_kernel(
    const float* __restrict__ qkv, const float* __restrict__ cosT,
    const float* __restrict__ sinT, short* __restrict__ qbf,
    short* __restrict__ kbf, short* __restrict__ vt)
{
    const int row  = blockIdx.x;      // b*2048 + l
    const int b    = row >> 11;
    const int l    = row & 2047;
    const int wave = threadIdx.x >> 6;
    const int lane = threadIdx.x & 63;
    const float* src = qkv + (size_t)row * 2304;
    const float c = cosT[l * 64 + lane];
    const float s = sinT[l * 64 + lane];

    for (int hh = wave; hh < 18; hh += 4) {
        if (hh < 17) {
            const float* base = src + ((hh < 16) ? hh * 128 : 2048);
            float x1 = base[lane];
            float x2 = base[lane + 64];
            float y1 =  x1 * c + x2 * s;
            float y2 = -x1 * s + x2 * c;
            float ss = y1 * y1 + y2 * y2;
            #pragma unroll
            for (int m = 32; m >= 1; m >>= 1) ss += __shfl_xor(ss, m, 64);
            float sc = rsqrtf(ss * (1.0f / 128.0f) + EPS_RMS);
            if (hh < 16) {
                sc *= INV_SQRT_HD;
                short* dst = qbf + ((size_t)(b * 16 + hh) * 2048 + l) * 128;
                dst[lane]      = f2bf(y1 * sc);
                dst[lane + 64] = f2bf(y2 * sc);
            } else {
                short* dst = kbf + (size_t)row * 128;
                dst[lane]      = f2bf(y1 * sc);
                dst[lane + 64] = f2bf(y2 * sc);
            }
        } else {
            const float* base = src + 2176;
            short* dst = vt + (size_t)b * 128 * 2048 + l;
            dst[(size_t)lane * 2048]        = f2bf(base[lane]);
            dst[(size_t)(lane + 64) * 2048] = f2bf(base[lane + 64]);
        }
    }
}

// ---------- kernel 4: causal MQA flash attention, split-KV x4 ----------
// One block per 32-row q-tile (grid 32 x 64, longest tiles first). The 4
// waves split the KV range in interleaved 64-kv chunks (j0 = wave*64 step
// 256), each keeping a private flash state (m, l, O^T in regs); epilogue
// merges the 4 partials via LDS (standard split-softmax combine).
// S^T = mfma(K, Q^T): lane&31 = q row, lane-local softmax; O^T = mfma(V^T,P^T).
__global__ __launch_bounds__(256, 6) void attn_kernel(
    const short* __restrict__ qbf, const short* __restrict__ kbf,
    const short* __restrict__ vt, short* __restrict__ obf)
{
    __shared__ float obuf[32][132];      // merge accumulator (+4 pad)
    __shared__ float mlbuf[2][4][32];    // [m|l][wave][row]
    const int tid  = threadIdx.x;
    const int wave = tid >> 6;
    const int lane = tid & 63;
    const int l31  = lane & 31;
    const int hi   = lane >> 5;

    const int gh = blockIdx.x;                 // 0..31 = b*16+h
    const int b  = gh >> 4;
    const int h  = gh & 15;
    const int tile = 63 - blockIdx.y;          // longest tiles dispatch first
    const int q0 = tile * 32;
    const int gq = q0 + l31;                   // this lane's q row

    const short* qp = qbf + ((size_t)(b * 16 + h) * 2048 + gq) * 128 + hi * 8;
    const short* kp = kbf + (size_t)b * 2048 * 128 + hi * 8;
    const short* vp = vt  + (size_t)b * 128 * 2048 + hi * 8;

    // Q fragments: B-operand of S^T (col = q). 8 k-slots of 16 over hd=128.
    bf16x8 qf[8];
    #pragma unroll
    for (int s = 0; s < 8; ++s) qf[s] = *(const bf16x8*)(qp + s * 16);

    f32x16 oacc[4];
    #pragma unroll
    for (int dt = 0; dt < 4; ++dt)
        #pragma unroll
        for (int r = 0; r < 16; ++r) oacc[dt][r] = 0.f;
    float m_run = 0.f, lsum = 0.f;

    for (int j0 = wave * 64; j0 < q0 + 32; j0 += 256) {
        const bool haveT1 = (j0 + 32) <= (q0 + 31);

        // ---- S^T = K · Q^T : two 32-kv tiles ----
        f32x16 s0a, s1a;
        #pragma unroll
        for (int r = 0; r < 16; ++r) { s0a[r] = 0.f; s1a[r] = NEGBIG; }

        const short* krow0 = kp + (size_t)(j0 + l31) * 128;
        #pragma unroll
        for (int s = 0; s < 8; ++s) {
            bf16x8 kf = *(const bf16x8*)(krow0 + s * 16);
            s0a = __builtin_amdgcn_mfma_f32_32x32x16_bf16(kf, qf[s], s0a, 0, 0, 0);
        }
        if (haveT1) {
            #pragma unroll
            for (int r = 0; r < 16; ++r) s1a[r] = 0.f;
            const short* krow1 = kp + (size_t)(j0 + 32 + l31) * 128;
            #pragma unroll
            for (int s = 0; s < 8; ++s) {
                bf16x8 kf = *(const bf16x8*)(krow1 + s * 16);
                s1a = __builtin_amdgcn_mfma_f32_32x32x16_bf16(kf, qf[s], s1a, 0, 0, 0);
            }
        }

        // ---- causal mask (diagonal-overlapping chunks only) ----
        if (j0 + 63 > q0) {
            #pragma unroll
            for (int r = 0; r < 16; ++r) {
                const int base = (r & 3) + 8 * (r >> 2) + 4 * hi;
                if (j0 + base > gq) s0a[r] = NEGBIG;
                if (haveT1 && (j0 + 32 + base > gq)) s1a[r] = NEGBIG;
            }
        }

        // ---- row max (in-register tree + one cross-half shuffle) ----
        float t8[8];
        #pragma unroll
        for (int r = 0; r < 8; ++r)
            t8[r] = fmaxf(fmaxf(s0a[r], s0a[r + 8]), fmaxf(s1a[r], s1a[r + 8]));
        #pragma unroll
        for (int r = 0; r < 4; ++r) t8[r] = fmaxf(t8[r], t8[r + 4]);
        float pmax = fmaxf(fmaxf(t8[0], t8[1]), fmaxf(t8[2], t8[3]));
        pmax = fmaxf(pmax, __shfl_xor(pmax, 32));

        // ---- defer-max rescale (T13, THR=8) ----
        if (!__all(pmax <= m_run + 8.0f)) {
            const float mnew  = fmaxf(m_run, pmax);
            const float alpha = __expf(m_run - mnew);
            #pragma unroll
            for (int dt = 0; dt < 4; ++dt)
                #pragma unroll
                for (int r = 0; r < 16; ++r) oacc[dt][r] *= alpha;
            lsum *= alpha;
            m_run = mnew;
        }

        // ---- P = exp(S - m), row sum ----
        float rs = 0.f;
        #pragma unroll
        for (int r = 0; r < 16; ++r) {
            s0a[r] = __expf(s0a[r] - m_run);
            s1a[r] = __expf(s1a[r] - m_run);
        }
        {
            float a8[8];
            #pragma unroll
            for (int r = 0; r < 8; ++r)
                a8[r] = (s0a[r] + s0a[r + 8]) + (s1a[r] + s1a[r + 8]);
            #pragma unroll
            for (int r = 0; r < 4; ++r) a8[r] += a8[r + 4];
            rs = (a8[0] + a8[1]) + (a8[2] + a8[3]);
        }
        rs += __shfl_xor(rs, 32);
        lsum += rs;

        // ---- P^T -> B-operand frags: pack pairs + exchange halves ----
        union FragU { unsigned int u[4]; bf16x8 v; };
        unsigned int W[8], X[8];
        #pragma unroll
        for (int jw = 0; jw < 8; ++jw) {
            W[jw] = pack2(s0a[2 * jw], s0a[2 * jw + 1]);
            X[jw] = (unsigned int)__shfl_xor((int)W[jw], 32);
        }
        FragU f0, f1;
        if (hi) {
            f0.u[0] = X[2]; f0.u[1] = X[3]; f0.u[2] = W[2]; f0.u[3] = W[3];
            f1.u[0] = X[6]; f1.u[1] = X[7]; f1.u[2] = W[6]; f1.u[3] = W[7];
        } else {
            f0.u[0] = W[0]; f0.u[1] = W[1]; f0.u[2] = X[0]; f0.u[3] = X[1];
            f1.u[0] = W[4]; f1.u[1] = W[5]; f1.u[2] = X[4]; f1.u[3] = X[5];
        }

        // ---- O^T += V^T · P^T  (slots 0,1 = kv j0..j0+31) ----
        #pragma unroll
        for (int dt = 0; dt < 4; ++dt) {
            const short* vrow = vp + (size_t)(dt * 32 + l31) * 2048 + j0;
            bf16x8 vf0 = *(const bf16x8*)(vrow);
            bf16x8 vf1 = *(const bf16x8*)(vrow + 16);
            oacc[dt] = __builtin_amdgcn_mfma_f32_32x32x16_bf16(vf0, f0.v, oacc[dt], 0, 0, 0);
            oacc[dt] = __builtin_amdgcn_mfma_f32_32x32x16_bf16(vf1, f1.v, oacc[dt], 0, 0, 0);
        }

        if (haveT1) {
            unsigned int W1[8], X1[8];
            #pragma unroll
            for (int jw = 0; jw < 8; ++jw) {
                W1[jw] = pack2(s1a[2 * jw], s1a[2 * jw + 1]);
                X1[jw] = (unsigned int)__shfl_xor((int)W1[jw], 32);
            }
            FragU f2, f3;
            if (hi) {
                f2.u[0] = X1[2]; f2.u[1] = X1[3]; f2.u[2] = W1[2]; f2.u[3] = W1[3];
                f3.u[0] = X1[6]; f3.u[1] = X1[7]; f3.u[2] = W1[6]; f3.u[3] = W1[7];
            } else {
                f2.u[0] = W1[0]; f2.u[1] = W1[1]; f2.u[2] = X1[0]; f2.u[3] = X1[1];
                f3.u[0] = W1[4]; f3.u[1] = W1[5]; f3.u[2] = X1[4]; f3.u[3] = X1[5];
            }
            #pragma unroll
            for (int dt = 0; dt < 4; ++dt) {
                const short* vrow = vp + (size_t)(dt * 32 + l31) * 2048 + j0;
                bf16x8 vf2 = *(const bf16x8*)(vrow + 32);
                bf16x8 vf3 = *(const bf16x8*)(vrow + 48);
                oacc[dt] = __builtin_amdgcn_mfma_f32_32x32x16_bf16(vf2, f2.v, oacc[dt], 0, 0, 0);
                oacc[dt] = __builtin_amdgcn_mfma_f32_32x32x16_bf16(vf3, f3.v, oacc[dt], 0, 0, 0);
            }
        }
    }

    // ---- split-KV merge: per-wave (m,l) to LDS, then serial O accumulate ----
    if (hi == 0) {
        mlbuf[0][wave][l31] = m_run;
        mlbuf[1][wave][l31] = lsum;
    }
    __syncthreads();
    float M = fmaxf(fmaxf(mlbuf[0][0][l31], mlbuf[0][1][l31]),
                    fmaxf(mlbuf[0][2][l31], mlbuf[0][3][l31]));
    const float alpha = __expf(m_run - M);

    #pragma unroll
    for (int w = 0; w < 4; ++w) {
        if (wave == w) {
            #pragma unroll
            for (int dt = 0; dt < 4; ++dt)
                #pragma unroll
                for (int a = 0; a < 4; ++a) {
                    float* dst = &obuf[l31][dt * 32 + a * 8 + hi * 4];
                    f32x4 val;
                    val[0] = alpha * oacc[dt][4 * a + 0];
                    val[1] = alpha * oacc[dt][4 * a + 1];
                    val[2] = alpha * oacc[dt][4 * a + 2];
                    val[3] = alpha * oacc[dt][4 * a + 3];
                    if (w == 0) *(f32x4*)dst = val;
                    else        *(f32x4*)dst = *(f32x4*)dst + val;
                }
        }
        __syncthreads();
    }

    // ---- normalize + store (thread t: row t>>3, d-segment (t&7)*16) ----
    {
        const int orow = tid >> 3;
        const int od   = (tid & 7) * 16;
        float m0 = mlbuf[0][0][orow], m1 = mlbuf[0][1][orow];
        float m2 = mlbuf[0][2][orow], m3 = mlbuf[0][3][orow];
        float Mr = fmaxf(fmaxf(m0, m1), fmaxf(m2, m3));
        float L = mlbuf[1][0][orow] * __expf(m0 - Mr) +
                  mlbuf[1][1][orow] * __expf(m1 - Mr) +
                  mlbuf[1][2][orow] * __expf(m2 - Mr) +
                  mlbuf[1][3][orow] * __expf(m3 - Mr);
        const float invL = 1.0f / L;
        short tmp[16];
        #pragma unroll
        for (int e = 0; e < 16; ++e)
            tmp[e] = f2bf(obuf[orow][od + e] * invL);
        short* orow_p = obf + ((size_t)b * 2048 + q0 + orow) * 2048 + h * 128 + od;
        *(bf16x8*)(orow_p)     = *(bf16x8*)(&tmp[0]);
        *(bf16x8*)(orow_p + 8) = *(bf16x8*)(&tmp[8]);
    }
}

// ---------- launch ----------
extern "C" void kernel_launch(void* const* d_in, const int* in_sizes, int n_in,
                              void* d_out, int out_size, void* d_ws, size_t ws_size,
                              hipStream_t stream)
{
    const float* x    = (const float*)d_in[0];
    const float* cosT = (const float*)d_in[1];
    const float* sinT = (const float*)d_in[2];
    const float* wq   = (const float*)d_in[3];
    const float* wk   = (const float*)d_in[4];
    const float* wv   = (const float*)d_in[5];
    const float* wo   = (const float*)d_in[6];
    float* out = (float*)d_out;

    char* ws = (char*)d_ws;
    size_t off = 0;
    auto alloc = [&](size_t bytes) {
        char* p = ws + off;
        off = (off + bytes + 255) & ~(size_t)255;
        return p;
    };
    short* x_bf  = (short*)alloc((size_t)4096 * 2048 * 2);   // also reused as attn_bf
    short* wcat  = (short*)alloc((size_t)2304 * 2048 * 2);   // [wq;wk;wv]
    short* wo_bf = (short*)alloc((size_t)2048 * 2048 * 2);
    float* qkv   = (float*)alloc((size_t)4096 * 2304 * 4);
    short* q_bf  = (short*)alloc((size_t)2 * 16 * 2048 * 128 * 2);
    short* k_bf  = (short*)alloc((size_t)2 * 2048 * 128 * 2);
    short* v_t   = (short*)alloc((size_t)2 * 128 * 2048 * 2);
    short* attn_bf = x_bf;  // x_bf dead after GEMM1; alias to save workspace
    (void)in_sizes; (void)n_in; (void)out_size; (void)ws_size;

    cvt_f32_bf16<<<1024, 256, 0, stream>>>(x, x_bf, 4096 * 2048);
    cvt_f32_bf16<<<512, 256, 0, stream>>>(wq, wcat, 2048 * 2048);
    cvt_f32_bf16<<<64, 256, 0, stream>>>(wk, wcat + (size_t)2048 * 2048, 128 * 2048);
    cvt_f32_bf16<<<64, 256, 0, stream>>>(wv, wcat + (size_t)2176 * 2048, 128 * 2048);
    cvt_f32_bf16<<<512, 256, 0, stream>>>(wo, wo_bf, 2048 * 2048);

    // qkv = x @ [wq;wk;wv]^T   (M=4096, N=2304, K=2048)
    gemm_bt<<<dim3(18, 32), 256, 0, stream>>>(x_bf, wcat, qkv, 4096, 2304, 2048);

    prep_kernel<<<4096, 256, 0, stream>>>(qkv, cosT, sinT, q_bf, k_bf, v_t);

    attn_kernel<<<dim3(32, 64), 256, 0, stream>>>(q_bf, k_bf, v_t, attn_bf);

    // out = attn @ wo^T   (M=4096, N=2048, K=2048)
    gemm_bt<<<dim3(16, 32), 256, 0, stream>>>(attn_bf, wo_bf, out, 4096, 2048, 2048);
}

// Round 7
// 300.293 us; speedup vs baseline: 2.7440x; 2.7440x over previous
//
#include <hip/hip_runtime.h>
#include <stdint.h>

// ---------- types ----------
typedef short bf16x8 __attribute__((ext_vector_type(8)));
typedef float f32x4  __attribute__((ext_vector_type(4)));
typedef float f32x16 __attribute__((ext_vector_type(16)));

#define EPS_RMS 1.1920929e-07f
#define INV_SQRT_HD 0.08838834764831845f  // 1/sqrt(128)
#define NEGBIG (-3.0e38f)

// f32 -> bf16 bits, round-to-nearest-even
__device__ __forceinline__ short f2bf(float f) {
    uint32_t u = __float_as_uint(f);
    u += 0x7fffu + ((u >> 16) & 1u);
    return (short)(u >> 16);
}

__device__ __forceinline__ unsigned int pack2(float lo, float hi) {
    return (unsigned int)(unsigned short)f2bf(lo) |
           ((unsigned int)(unsigned short)f2bf(hi) << 16);
}

using gld_t = const __attribute__((address_space(1))) unsigned int*;
using lds_t = __attribute__((address_space(3))) unsigned int*;

// async global->LDS, 16 bytes per lane (lane i lands at ldsbase + i*16)
__device__ __forceinline__ void glds16(const short* g, short* l) {
    __builtin_amdgcn_global_load_lds((gld_t)g, (lds_t)l, 16, 0, 0);
}

// ---------- kernel 1: f32 -> bf16 convert (vectorized x4) ----------
__global__ void cvt_f32_bf16(const float* __restrict__ in, short* __restrict__ out, int n) {
    int i = (blockIdx.x * blockDim.x + threadIdx.x) * 4;
    int stride = gridDim.x * blockDim.x * 4;
    for (; i < n; i += stride) {
        float4 v = *(const float4*)(in + i);
        short4 o;
        o.x = f2bf(v.x); o.y = f2bf(v.y); o.z = f2bf(v.z); o.w = f2bf(v.w);
        *(short4*)(out + i) = o;
    }
}

// ---------- kernel 2: C[M,N] = A[M,K] * Bw[N,K]^T  (bf16 in, f32 out) ----------
__global__ __launch_bounds__(256, 1) void gemm_bt(
    const short* __restrict__ A, const short* __restrict__ Bw,
    float* __restrict__ C, int M, int N, int K)
{
    __shared__ short sA[128 * 32];
    __shared__ short sB[128 * 32];
    const int tid  = threadIdx.x;
    const int lane = tid & 63;
    const int wave = tid >> 6;
    const int wm = (wave >> 1) * 64;
    const int wn = (wave & 1) * 64;
    const size_t row0 = (size_t)blockIdx.y * 128;
    const size_t col0 = (size_t)blockIdx.x * 128;
    const int fr = lane & 15;
    const int fk = (lane >> 4) * 8;

    f32x4 acc[4][4] = {};

    const short* gA = A + (row0 + (tid >> 2)) * (size_t)K + (tid & 3) * 8;
    const short* gB = Bw + (col0 + (tid >> 2)) * (size_t)K + (tid & 3) * 8;
    short* lA = sA + tid * 8;
    short* lB = sB + tid * 8;

    for (int k0 = 0; k0 < K; k0 += 32) {
        glds16(gA + k0, lA);
        glds16(gA + k0 + (size_t)64 * K, lA + 2048);
        glds16(gB + k0, lB);
        glds16(gB + k0 + (size_t)64 * K, lB + 2048);
        __syncthreads();

        bf16x8 af[4], bb[4];
        #pragma unroll
        for (int m = 0; m < 4; ++m)
            af[m] = *(const bf16x8*)(sA + (wm + m * 16 + fr) * 32 + fk);
        #pragma unroll
        for (int n = 0; n < 4; ++n)
            bb[n] = *(const bf16x8*)(sB + (wn + n * 16 + fr) * 32 + fk);
        #pragma unroll
        for (int m = 0; m < 4; ++m)
            #pragma unroll
            for (int n = 0; n < 4; ++n)
                acc[m][n] = __builtin_amdgcn_mfma_f32_16x16x32_bf16(af[m], bb[n], acc[m][n], 0, 0, 0);
        __syncthreads();
    }

    const int cr = (lane >> 4) * 4;
    #pragma unroll
    for (int m = 0; m < 4; ++m)
        #pragma unroll
        for (int n = 0; n < 4; ++n)
            #pragma unroll
            for (int r = 0; r < 4; ++r)
                C[(row0 + wm + m * 16 + cr + r) * N + col0 + wn + n * 16 + fr] = acc[m][n][r];
}

// ---------- kernel 3: RoPE + RMSNorm for q,k; convert+transpose v ----------
__global__ __launch_bounds__(256, 1) void prep_kernel(
    const float* __restrict__ qkv, const float* __restrict__ cosT,
    const float* __restrict__ sinT, short* __restrict__ qbf,
    short* __restrict__ kbf, short* __restrict__ vt)
{
    const int row  = blockIdx.x;      // b*2048 + l
    const int b    = row >> 11;
    const int l    = row & 2047;
    const int wave = threadIdx.x >> 6;
    const int lane = threadIdx.x & 63;
    const float* src = qkv + (size_t)row * 2304;
    const float c = cosT[l * 64 + lane];
    const float s = sinT[l * 64 + lane];

    for (int hh = wave; hh < 18; hh += 4) {
        if (hh < 17) {
            const float* base = src + ((hh < 16) ? hh * 128 : 2048);
            float x1 = base[lane];
            float x2 = base[lane + 64];
            float y1 =  x1 * c + x2 * s;
            float y2 = -x1 * s + x2 * c;
            float ss = y1 * y1 + y2 * y2;
            #pragma unroll
            for (int m = 32; m >= 1; m >>= 1) ss += __shfl_xor(ss, m, 64);
            float sc = rsqrtf(ss * (1.0f / 128.0f) + EPS_RMS);
            if (hh < 16) {
                sc *= INV_SQRT_HD;
                short* dst = qbf + ((size_t)(b * 16 + hh) * 2048 + l) * 128;
                dst[lane]      = f2bf(y1 * sc);
                dst[lane + 64] = f2bf(y2 * sc);
            } else {
                short* dst = kbf + (size_t)row * 128;
                dst[lane]      = f2bf(y1 * sc);
                dst[lane + 64] = f2bf(y2 * sc);
            }
        } else {
            const float* base = src + 2176;
            short* dst = vt + (size_t)b * 128 * 2048 + l;
            dst[(size_t)lane * 2048]        = f2bf(base[lane]);
            dst[(size_t)(lane + 64) * 2048] = f2bf(base[lane + 64]);
        }
    }
}

// ---------- attention chunk body (64 kv cols = two 32x32 tiles) ----------
// Scores are bounded (|s| <= ~11.4 after RMS-norm + 1/sqrt(hd) folding), so
// P = exp(S) directly -- no max tracking, no rescale. MASKED: apply causal
// mask (diagonal chunk only). HAVET1: second 32-kv tile exists.
template<bool MASKED, bool HAVET1>
__device__ __forceinline__ void attn_chunk(
    int j0, int gq, int hi, int l31,
    const short* __restrict__ kp, const short* __restrict__ vp,
    const bf16x8 (&qf)[8], f32x16 (&oacc)[4], float& lsum)
{
    union FragU { unsigned int u[4]; bf16x8 v; };
    f32x16 s0, s1;
    #pragma unroll
    for (int r = 0; r < 16; ++r) s0[r] = 0.f;

    const short* krow0 = kp + (size_t)(j0 + l31) * 128;
    #pragma unroll
    for (int s = 0; s < 8; ++s) {
        bf16x8 kf = *(const bf16x8*)(krow0 + s * 16);
        s0 = __builtin_amdgcn_mfma_f32_32x32x16_bf16(kf, qf[s], s0, 0, 0, 0);
    }
    if (HAVET1) {
        #pragma unroll
        for (int r = 0; r < 16; ++r) s1[r] = 0.f;
        const short* krow1 = krow0 + 32 * 128;
        #pragma unroll
        for (int s = 0; s < 8; ++s) {
            bf16x8 kf = *(const bf16x8*)(krow1 + s * 16);
            s1 = __builtin_amdgcn_mfma_f32_32x32x16_bf16(kf, qf[s], s1, 0, 0, 0);
        }
    }

    if (MASKED) {
        #pragma unroll
        for (int r = 0; r < 16; ++r) {
            const int base = (r & 3) + 8 * (r >> 2) + 4 * hi;
            if (j0 + base > gq) s0[r] = NEGBIG;
            if (HAVET1 && (j0 + 32 + base > gq)) s1[r] = NEGBIG;
        }
    }

    // P = exp(S)  (bounded scores; masked lanes underflow to 0)
    #pragma unroll
    for (int r = 0; r < 16; ++r) {
        s0[r] = __expf(s0[r]);
        if (HAVET1) s1[r] = __expf(s1[r]);
    }

    // row sum (off the PV critical path)
    {
        float a8[8];
        #pragma unroll
        for (int r = 0; r < 8; ++r)
            a8[r] = HAVET1 ? (s0[r] + s0[r + 8]) + (s1[r] + s1[r + 8])
                           : (s0[r] + s0[r + 8]);
        #pragma unroll
        for (int r = 0; r < 4; ++r) a8[r] += a8[r + 4];
        float rs = (a8[0] + a8[1]) + (a8[2] + a8[3]);
        rs += __shfl_xor(rs, 32);
        lsum += rs;
    }

    // P^T tile0 -> B-operand frags (pack pairs + exchange halves), PV MFMA
    {
        unsigned int W[8], X[8];
        #pragma unroll
        for (int jw = 0; jw < 8; ++jw) {
            W[jw] = pack2(s0[2 * jw], s0[2 * jw + 1]);
            X[jw] = (unsigned int)__shfl_xor((int)W[jw], 32);
        }
        FragU f0, f1;
        if (hi) {
            f0.u[0] = X[2]; f0.u[1] = X[3]; f0.u[2] = W[2]; f0.u[3] = W[3];
            f1.u[0] = X[6]; f1.u[1] = X[7]; f1.u[2] = W[6]; f1.u[3] = W[7];
        } else {
            f0.u[0] = W[0]; f0.u[1] = W[1]; f0.u[2] = X[0]; f0.u[3] = X[1];
            f1.u[0] = W[4]; f1.u[1] = W[5]; f1.u[2] = X[4]; f1.u[3] = X[5];
        }
        #pragma unroll
        for (int dt = 0; dt < 4; ++dt) {
            const short* vrow = vp + (size_t)(dt * 32 + l31) * 2048 + j0;
            bf16x8 vf0 = *(const bf16x8*)(vrow);
            bf16x8 vf1 = *(const bf16x8*)(vrow + 16);
            oacc[dt] = __builtin_amdgcn_mfma_f32_32x32x16_bf16(vf0, f0.v, oacc[dt], 0, 0, 0);
            oacc[dt] = __builtin_amdgcn_mfma_f32_32x32x16_bf16(vf1, f1.v, oacc[dt], 0, 0, 0);
        }
    }

    if (HAVET1) {
        unsigned int W[8], X[8];
        #pragma unroll
        for (int jw = 0; jw < 8; ++jw) {
            W[jw] = pack2(s1[2 * jw], s1[2 * jw + 1]);
            X[jw] = (unsigned int)__shfl_xor((int)W[jw], 32);
        }
        FragU f2, f3;
        if (hi) {
            f2.u[0] = X[2]; f2.u[1] = X[3]; f2.u[2] = W[2]; f2.u[3] = W[3];
            f3.u[0] = X[6]; f3.u[1] = X[7]; f3.u[2] = W[6]; f3.u[3] = W[7];
        } else {
            f2.u[0] = W[0]; f2.u[1] = W[1]; f2.u[2] = X[0]; f2.u[3] = X[1];
            f3.u[0] = W[4]; f3.u[1] = W[5]; f3.u[2] = X[4]; f3.u[3] = X[5];
        }
        #pragma unroll
        for (int dt = 0; dt < 4; ++dt) {
            const short* vrow = vp + (size_t)(dt * 32 + l31) * 2048 + j0;
            bf16x8 vf2 = *(const bf16x8*)(vrow + 32);
            bf16x8 vf3 = *(const bf16x8*)(vrow + 48);
            oacc[dt] = __builtin_amdgcn_mfma_f32_32x32x16_bf16(vf2, f2.v, oacc[dt], 0, 0, 0);
            oacc[dt] = __builtin_amdgcn_mfma_f32_32x32x16_bf16(vf3, f3.v, oacc[dt], 0, 0, 0);
        }
    }
}

// ---------- kernel 4: causal MQA flash attention, one wave per q-tile ----------
// Grid (32 heads, 64 q-tiles), 64-thread blocks, longest tiles first; 2048
// independent single-wave blocks (all co-resident at ~10 waves/CU) -> no
// cross-wave communication anywhere, deterministic by construction.
// S^T = mfma(K, Q^T): lane&31 = q row, lane-local softmax (bounded scores,
// no max tracking); O^T = mfma(V^T, P^T). Epilogue: per-wave LDS transpose.
__global__ __launch_bounds__(64, 2) void attn_kernel(
    const short* __restrict__ qbf, const short* __restrict__ kbf,
    const short* __restrict__ vt, short* __restrict__ obf)
{
    __shared__ short o_sh[32][136];   // +8 pad: conflict-free epilogue
    const int lane = threadIdx.x & 63;
    const int l31  = lane & 31;
    const int hi   = lane >> 5;

    const int gh = blockIdx.x;                 // 0..31 = b*16+h
    const int b  = gh >> 4;
    const int h  = gh & 15;
    const int tile = 63 - blockIdx.y;          // longest tiles dispatch first
    const int q0 = tile * 32;
    const int gq = q0 + l31;                   // this lane's q row

    const short* qp = qbf + ((size_t)(b * 16 + h) * 2048 + gq) * 128 + hi * 8;
    const short* kp = kbf + (size_t)b * 2048 * 128 + hi * 8;
    const short* vp = vt  + (size_t)b * 128 * 2048 + hi * 8;

    // Q fragments: B-operand of S^T (col = q). 8 k-slots of 16 over hd=128.
    bf16x8 qf[8];
    #pragma unroll
    for (int s = 0; s < 8; ++s) qf[s] = *(const bf16x8*)(qp + s * 16);

    f32x16 oacc[4];
    #pragma unroll
    for (int dt = 0; dt < 4; ++dt)
        #pragma unroll
        for (int r = 0; r < 16; ++r) oacc[dt][r] = 0.f;
    float lsum = 0.f;

    // steady state: full unmasked chunks (j0+63 <= q0 for all lanes' gq)
    int j0 = 0;
    for (; j0 < q0 - 32; j0 += 64)
        attn_chunk<false, true>(j0, gq, hi, l31, kp, vp, qf, oacc, lsum);
    // exactly one diagonal (masked) tail chunk: j0 <= q0 < j0+64 here
    if (j0 < q0) attn_chunk<true, true >(j0, gq, hi, l31, kp, vp, qf, oacc, lsum);
    else         attn_chunk<true, false>(j0, gq, hi, l31, kp, vp, qf, oacc, lsum);

    // ---- epilogue: normalize, transpose via LDS (wave-private), store ----
    const float inv = 1.0f / lsum;
    #pragma unroll
    for (int dt = 0; dt < 4; ++dt)
        #pragma unroll
        for (int r = 0; r < 16; ++r) {
            const int d = dt * 32 + (r & 3) + 8 * (r >> 2) + 4 * hi;
            o_sh[l31][d] = f2bf(oacc[dt][r] * inv);
        }
    __syncthreads();
    const int rlane = lane >> 4;       // 0..3
    const int dl = (lane & 15) * 8;
    #pragma unroll
    for (int pass = 0; pass < 8; ++pass) {
        const int row = pass * 4 + rlane;
        bf16x8 ov = *(const bf16x8*)(&o_sh[row][dl]);
        *(bf16x8*)(obf + ((size_t)b * 2048 + q0 + row) * 2048 + h * 128 + dl) = ov;
    }
}

// ---------- launch ----------
extern "C" void kernel_launch(void* const* d_in, const int* in_sizes, int n_in,
                              void* d_out, int out_size, void* d_ws, size_t ws_size,
                              hipStream_t stream)
{
    const float* x    = (const float*)d_in[0];
    const float* cosT = (const float*)d_in[1];
    const float* sinT = (const float*)d_in[2];
    const float* wq   = (const float*)d_in[3];
    const float* wk   = (const float*)d_in[4];
    const float* wv   = (const float*)d_in[5];
    const float* wo   = (const float*)d_in[6];
    float* out = (float*)d_out;

    char* ws = (char*)d_ws;
    size_t off = 0;
    auto alloc = [&](size_t bytes) {
        char* p = ws + off;
        off = (off + bytes + 255) & ~(size_t)255;
        return p;
    };
    short* x_bf  = (short*)alloc((size_t)4096 * 2048 * 2);   // also reused as attn_bf
    short* wcat  = (short*)alloc((size_t)2304 * 2048 * 2);   // [wq;wk;wv]
    short* wo_bf = (short*)alloc((size_t)2048 * 2048 * 2);
    float* qkv   = (float*)alloc((size_t)4096 * 2304 * 4);
    short* q_bf  = (short*)alloc((size_t)2 * 16 * 2048 * 128 * 2);
    short* k_bf  = (short*)alloc((size_t)2 * 2048 * 128 * 2);
    short* v_t   = (short*)alloc((size_t)2 * 128 * 2048 * 2);
    short* attn_bf = x_bf;  // x_bf dead after GEMM1; alias to save workspace
    (void)in_sizes; (void)n_in; (void)out_size; (void)ws_size;

    cvt_f32_bf16<<<1024, 256, 0, stream>>>(x, x_bf, 4096 * 2048);
    cvt_f32_bf16<<<512, 256, 0, stream>>>(wq, wcat, 2048 * 2048);
    cvt_f32_bf16<<<64, 256, 0, stream>>>(wk, wcat + (size_t)2048 * 2048, 128 * 2048);
    cvt_f32_bf16<<<64, 256, 0, stream>>>(wv, wcat + (size_t)2176 * 2048, 128 * 2048);
    cvt_f32_bf16<<<512, 256, 0, stream>>>(wo, wo_bf, 2048 * 2048);

    // qkv = x @ [wq;wk;wv]^T   (M=4096, N=2304, K=2048)
    gemm_bt<<<dim3(18, 32), 256, 0, stream>>>(x_bf, wcat, qkv, 4096, 2304, 2048);

    prep_kernel<<<4096, 256, 0, stream>>>(qkv, cosT, sinT, q_bf, k_bf, v_t);

    attn_kernel<<<dim3(32, 64), 64, 0, stream>>>(q_bf, k_bf, v_t, attn_bf);

    // out = attn @ wo^T   (M=4096, N=2048, K=2048)
    gemm_bt<<<dim3(16, 32), 256, 0, stream>>>(attn_bf, wo_bf, out, 4096, 2048, 2048);
}

// Round 9
// 299.130 us; speedup vs baseline: 2.7547x; 1.0039x over previous
//
#include <hip/hip_runtime.h>
#include <stdint.h>

// ---------- types ----------
typedef short bf16x8 __attribute__((ext_vector_type(8)));
typedef float f32x4  __attribute__((ext_vector_type(4)));
typedef float f32x16 __attribute__((ext_vector_type(16)));
typedef int   i32x2  __attribute__((ext_vector_type(2)));

#define EPS_RMS 1.1920929e-07f
#define INV_SQRT_HD 0.08838834764831845f  // 1/sqrt(128)
#define NEGBIG (-3.0e38f)

// f32 -> bf16 bits, round-to-nearest-even (scalar, epilogue/convert use)
__device__ __forceinline__ short f2bf(float f) {
    uint32_t u = __float_as_uint(f);
    u += 0x7fffu + ((u >> 16) & 1u);
    return (short)(u >> 16);
}

// packed f32x2 -> bf16x2 in one VALU op (T12 recipe; no builtin on gfx950)
__device__ __forceinline__ unsigned int cvtpk(float lo, float hi) {
    unsigned int r;
    asm("v_cvt_pk_bf16_f32 %0, %1, %2" : "=v"(r) : "v"(lo), "v"(hi));
    return r;
}

// v_permlane32_swap_b32: x = {a.lo | b.lo->hi}, y = {a.hi->lo | b.hi}
__device__ __forceinline__ void halfswap(unsigned int a, unsigned int b,
                                         unsigned int& x, unsigned int& y) {
    i32x2 r = __builtin_amdgcn_permlane32_swap((int)a, (int)b, false, false);
    x = (unsigned int)r.x;
    y = (unsigned int)r.y;
}

using gld_t = const __attribute__((address_space(1))) unsigned int*;
using lds_t = __attribute__((address_space(3))) unsigned int*;

// async global->LDS, 16 bytes per lane (lane i lands at ldsbase + i*16)
__device__ __forceinline__ void glds16(const short* g, short* l) {
    __builtin_amdgcn_global_load_lds((gld_t)g, (lds_t)l, 16, 0, 0);
}

// ---------- kernel 1: f32 -> bf16 convert (vectorized x4) ----------
__global__ void cvt_f32_bf16(const float* __restrict__ in, short* __restrict__ out, int n) {
    int i = (blockIdx.x * blockDim.x + threadIdx.x) * 4;
    int stride = gridDim.x * blockDim.x * 4;
    for (; i < n; i += stride) {
        float4 v = *(const float4*)(in + i);
        short4 o;
        o.x = f2bf(v.x); o.y = f2bf(v.y); o.z = f2bf(v.z); o.w = f2bf(v.w);
        *(short4*)(out + i) = o;
    }
}

// ---------- kernel 2: C[M,N] = A[M,K] * Bw[N,K]^T  (bf16 in, f32 out) ----------
__global__ __launch_bounds__(256, 1) void gemm_bt(
    const short* __restrict__ A, const short* __restrict__ Bw,
    float* __restrict__ C, int M, int N, int K)
{
    __shared__ short sA[128 * 32];
    __shared__ short sB[128 * 32];
    const int tid  = threadIdx.x;
    const int lane = tid & 63;
    const int wave = tid >> 6;
    const int wm = (wave >> 1) * 64;
    const int wn = (wave & 1) * 64;
    const size_t row0 = (size_t)blockIdx.y * 128;
    const size_t col0 = (size_t)blockIdx.x * 128;
    const int fr = lane & 15;
    const int fk = (lane >> 4) * 8;

    f32x4 acc[4][4] = {};

    const short* gA = A + (row0 + (tid >> 2)) * (size_t)K + (tid & 3) * 8;
    const short* gB = Bw + (col0 + (tid >> 2)) * (size_t)K + (tid & 3) * 8;
    short* lA = sA + tid * 8;
    short* lB = sB + tid * 8;

    for (int k0 = 0; k0 < K; k0 += 32) {
        glds16(gA + k0, lA);
        glds16(gA + k0 + (size_t)64 * K, lA + 2048);
        glds16(gB + k0, lB);
        glds16(gB + k0 + (size_t)64 * K, lB + 2048);
        __syncthreads();

        bf16x8 af[4], bb[4];
        #pragma unroll
        for (int m = 0; m < 4; ++m)
            af[m] = *(const bf16x8*)(sA + (wm + m * 16 + fr) * 32 + fk);
        #pragma unroll
        for (int n = 0; n < 4; ++n)
            bb[n] = *(const bf16x8*)(sB + (wn + n * 16 + fr) * 32 + fk);
        #pragma unroll
        for (int m = 0; m < 4; ++m)
            #pragma unroll
            for (int n = 0; n < 4; ++n)
                acc[m][n] = __builtin_amdgcn_mfma_f32_16x16x32_bf16(af[m], bb[n], acc[m][n], 0, 0, 0);
        __syncthreads();
    }

    const int cr = (lane >> 4) * 4;
    #pragma unroll
    for (int m = 0; m < 4; ++m)
        #pragma unroll
        for (int n = 0; n < 4; ++n)
            #pragma unroll
            for (int r = 0; r < 4; ++r)
                C[(row0 + wm + m * 16 + cr + r) * N + col0 + wn + n * 16 + fr] = acc[m][n][r];
}

// ---------- kernel 3: RoPE + RMSNorm for q,k; convert+transpose v ----------
__global__ __launch_bounds__(256, 1) void prep_kernel(
    const float* __restrict__ qkv, const float* __restrict__ cosT,
    const float* __restrict__ sinT, short* __restrict__ qbf,
    short* __restrict__ kbf, short* __restrict__ vt)
{
    const int row  = blockIdx.x;      // b*2048 + l
    const int b    = row >> 11;
    const int l    = row & 2047;
    const int wave = threadIdx.x >> 6;
    const int lane = threadIdx.x & 63;
    const float* src = qkv + (size_t)row * 2304;
    const float c = cosT[l * 64 + lane];
    const float s = sinT[l * 64 + lane];

    for (int hh = wave; hh < 18; hh += 4) {
        if (hh < 17) {
            const float* base = src + ((hh < 16) ? hh * 128 : 2048);
            float x1 = base[lane];
            float x2 = base[lane + 64];
            float y1 =  x1 * c + x2 * s;
            float y2 = -x1 * s + x2 * c;
            float ss = y1 * y1 + y2 * y2;
            #pragma unroll
            for (int m = 32; m >= 1; m >>= 1) ss += __shfl_xor(ss, m, 64);
            float sc = rsqrtf(ss * (1.0f / 128.0f) + EPS_RMS);
            if (hh < 16) {
                sc *= INV_SQRT_HD;
                short* dst = qbf + ((size_t)(b * 16 + hh) * 2048 + l) * 128;
                dst[lane]      = f2bf(y1 * sc);
                dst[lane + 64] = f2bf(y2 * sc);
            } else {
                short* dst = kbf + (size_t)row * 128;
                dst[lane]      = f2bf(y1 * sc);
                dst[lane + 64] = f2bf(y2 * sc);
            }
        } else {
            const float* base = src + 2176;
            short* dst = vt + (size_t)b * 128 * 2048 + l;
            dst[(size_t)lane * 2048]        = f2bf(base[lane]);
            dst[(size_t)(lane + 64) * 2048] = f2bf(base[lane + 64]);
        }
    }
}

// ---------- attention chunk body (64 kv cols = two 32x32 tiles) ----------
// Scores bounded (|s| <= ~11.4 after RMS-norm + 1/sqrt(hd) folding):
// P = exp(S) directly, no max tracking. P^T -> B-operand via
// v_cvt_pk_bf16_f32 + v_permlane32_swap (T12): swap(W0,W2) yields both
// fragment words {lo:W0|hi:X2} and {lo:X0|hi:W2} in one instruction.
// lsum accumulates per-lane half sums; cross-half reduce deferred to epilogue.
template<bool MASKED, bool HAVET1>
__device__ __forceinline__ void attn_chunk(
    int j0, int gq, int hi, int l31,
    const short* __restrict__ kp, const short* __restrict__ vp,
    const bf16x8 (&qf)[8], f32x16 (&oacc)[4], float& lsum)
{
    union FragU { unsigned int u[4]; bf16x8 v; };
    f32x16 s0, s1;
    #pragma unroll
    for (int r = 0; r < 16; ++r) s0[r] = 0.f;

    const short* krow0 = kp + (size_t)(j0 + l31) * 128;
    #pragma unroll
    for (int s = 0; s < 8; ++s) {
        bf16x8 kf = *(const bf16x8*)(krow0 + s * 16);
        s0 = __builtin_amdgcn_mfma_f32_32x32x16_bf16(kf, qf[s], s0, 0, 0, 0);
    }
    if (HAVET1) {
        #pragma unroll
        for (int r = 0; r < 16; ++r) s1[r] = 0.f;
        const short* krow1 = krow0 + 32 * 128;
        #pragma unroll
        for (int s = 0; s < 8; ++s) {
            bf16x8 kf = *(const bf16x8*)(krow1 + s * 16);
            s1 = __builtin_amdgcn_mfma_f32_32x32x16_bf16(kf, qf[s], s1, 0, 0, 0);
        }
    }

    if (MASKED) {
        #pragma unroll
        for (int r = 0; r < 16; ++r) {
            const int base = (r & 3) + 8 * (r >> 2) + 4 * hi;
            if (j0 + base > gq) s0[r] = NEGBIG;
            if (HAVET1 && (j0 + 32 + base > gq)) s1[r] = NEGBIG;
        }
    }

    // P = exp(S)  (bounded scores; masked lanes underflow to 0)
    #pragma unroll
    for (int r = 0; r < 16; ++r) {
        s0[r] = __expf(s0[r]);
        if (HAVET1) s1[r] = __expf(s1[r]);
    }

    // per-lane half row sum (cross-half reduce deferred to epilogue)
    {
        float a8[8];
        #pragma unroll
        for (int r = 0; r < 8; ++r)
            a8[r] = HAVET1 ? (s0[r] + s0[r + 8]) + (s1[r] + s1[r + 8])
                           : (s0[r] + s0[r + 8]);
        #pragma unroll
        for (int r = 0; r < 4; ++r) a8[r] += a8[r + 4];
        lsum += (a8[0] + a8[1]) + (a8[2] + a8[3]);
    }

    // P^T tile0 -> B-operand frags (cvt_pk + permlane32_swap), PV MFMA
    {
        unsigned int W[8];
        #pragma unroll
        for (int jw = 0; jw < 8; ++jw)
            W[jw] = cvtpk(s0[2 * jw], s0[2 * jw + 1]);
        FragU f0, f1;
        halfswap(W[0], W[2], f0.u[0], f0.u[2]);
        halfswap(W[1], W[3], f0.u[1], f0.u[3]);
        halfswap(W[4], W[6], f1.u[0], f1.u[2]);
        halfswap(W[5], W[7], f1.u[1], f1.u[3]);
        #pragma unroll
        for (int dt = 0; dt < 4; ++dt) {
            const short* vrow = vp + (size_t)(dt * 32 + l31) * 2048 + j0;
            bf16x8 vf0 = *(const bf16x8*)(vrow);
            bf16x8 vf1 = *(const bf16x8*)(vrow + 16);
            oacc[dt] = __builtin_amdgcn_mfma_f32_32x32x16_bf16(vf0, f0.v, oacc[dt], 0, 0, 0);
            oacc[dt] = __builtin_amdgcn_mfma_f32_32x32x16_bf16(vf1, f1.v, oacc[dt], 0, 0, 0);
        }
    }

    if (HAVET1) {
        unsigned int W[8];
        #pragma unroll
        for (int jw = 0; jw < 8; ++jw)
            W[jw] = cvtpk(s1[2 * jw], s1[2 * jw + 1]);
        FragU f2, f3;
        halfswap(W[0], W[2], f2.u[0], f2.u[2]);
        halfswap(W[1], W[3], f2.u[1], f2.u[3]);
        halfswap(W[4], W[6], f3.u[0], f3.u[2]);
        halfswap(W[5], W[7], f3.u[1], f3.u[3]);
        #pragma unroll
        for (int dt = 0; dt < 4; ++dt) {
            const short* vrow = vp + (size_t)(dt * 32 + l31) * 2048 + j0;
            bf16x8 vf2 = *(const bf16x8*)(vrow + 32);
            bf16x8 vf3 = *(const bf16x8*)(vrow + 48);
            oacc[dt] = __builtin_amdgcn_mfma_f32_32x32x16_bf16(vf2, f2.v, oacc[dt], 0, 0, 0);
            oacc[dt] = __builtin_amdgcn_mfma_f32_32x32x16_bf16(vf3, f3.v, oacc[dt], 0, 0, 0);
        }
    }
}

// ---------- kernel 4: causal MQA flash attention, one wave per q-tile ----------
// Grid (32 heads, 64 q-tiles), 64-thread blocks, longest tiles first; 2048
// independent single-wave blocks (all co-resident) -> no cross-wave
// communication anywhere, deterministic by construction.
// S^T = mfma(K, Q^T): lane&31 = q row, lane-local softmax (bounded scores,
// no max tracking); O^T = mfma(V^T, P^T). Epilogue: per-wave LDS transpose.
__global__ __launch_bounds__(64, 2) void attn_kernel(
    const short* __restrict__ qbf, const short* __restrict__ kbf,
    const short* __restrict__ vt, short* __restrict__ obf)
{
    __shared__ short o_sh[32][136];   // +8 pad: conflict-free epilogue
    const int lane = threadIdx.x & 63;
    const int l31  = lane & 31;
    const int hi   = lane >> 5;

    const int gh = blockIdx.x;                 // 0..31 = b*16+h
    const int b  = gh >> 4;
    const int h  = gh & 15;
    const int tile = 63 - blockIdx.y;          // longest tiles dispatch first
    const int q0 = tile * 32;
    const int gq = q0 + l31;                   // this lane's q row

    const short* qp = qbf + ((size_t)(b * 16 + h) * 2048 + gq) * 128 + hi * 8;
    const short* kp = kbf + (size_t)b * 2048 * 128 + hi * 8;
    const short* vp = vt  + (size_t)b * 128 * 2048 + hi * 8;

    // Q fragments: B-operand of S^T (col = q). 8 k-slots of 16 over hd=128.
    bf16x8 qf[8];
    #pragma unroll
    for (int s = 0; s < 8; ++s) qf[s] = *(const bf16x8*)(qp + s * 16);

    f32x16 oacc[4];
    #pragma unroll
    for (int dt = 0; dt < 4; ++dt)
        #pragma unroll
        for (int r = 0; r < 16; ++r) oacc[dt][r] = 0.f;
    float lsum = 0.f;

    // steady state: full unmasked chunks (j0+63 <= q0 for all lanes' gq)
    int j0 = 0;
    for (; j0 < q0 - 32; j0 += 64)
        attn_chunk<false, true>(j0, gq, hi, l31, kp, vp, qf, oacc, lsum);
    // exactly one diagonal (masked) tail chunk: j0 <= q0 < j0+64 here
    if (j0 < q0) attn_chunk<true, true >(j0, gq, hi, l31, kp, vp, qf, oacc, lsum);
    else         attn_chunk<true, false>(j0, gq, hi, l31, kp, vp, qf, oacc, lsum);

    // complete the deferred cross-half row-sum reduce
    lsum += __shfl_xor(lsum, 32);

    // ---- epilogue: normalize, transpose via LDS (wave-private), store ----
    const float inv = 1.0f / lsum;
    #pragma unroll
    for (int dt = 0; dt < 4; ++dt)
        #pragma unroll
        for (int r = 0; r < 16; ++r) {
            const int d = dt * 32 + (r & 3) + 8 * (r >> 2) + 4 * hi;
            o_sh[l31][d] = f2bf(oacc[dt][r] * inv);
        }
    __syncthreads();
    const int rlane = lane >> 4;       // 0..3
    const int dl = (lane & 15) * 8;
    #pragma unroll
    for (int pass = 0; pass < 8; ++pass) {
        const int row = pass * 4 + rlane;
        bf16x8 ov = *(const bf16x8*)(&o_sh[row][dl]);
        *(bf16x8*)(obf + ((size_t)b * 2048 + q0 + row) * 2048 + h * 128 + dl) = ov;
    }
}

// ---------- launch ----------
extern "C" void kernel_launch(void* const* d_in, const int* in_sizes, int n_in,
                              void* d_out, int out_size, void* d_ws, size_t ws_size,
                              hipStream_t stream)
{
    const float* x    = (const float*)d_in[0];
    const float* cosT = (const float*)d_in[1];
    const float* sinT = (const float*)d_in[2];
    const float* wq   = (const float*)d_in[3];
    const float* wk   = (const float*)d_in[4];
    const float* wv   = (const float*)d_in[5];
    const float* wo   = (const float*)d_in[6];
    float* out = (float*)d_out;

    char* ws = (char*)d_ws;
    size_t off = 0;
    auto alloc = [&](size_t bytes) {
        char* p = ws + off;
        off = (off + bytes + 255) & ~(size_t)255;
        return p;
    };
    short* x_bf  = (short*)alloc((size_t)4096 * 2048 * 2);   // also reused as attn_bf
    short* wcat  = (short*)alloc((size_t)2304 * 2048 * 2);   // [wq;wk;wv]
    short* wo_bf = (short*)alloc((size_t)2048 * 2048 * 2);
    float* qkv   = (float*)alloc((size_t)4096 * 2304 * 4);
    short* q_bf  = (short*)alloc((size_t)2 * 16 * 2048 * 128 * 2);
    short* k_bf  = (short*)alloc((size_t)2 * 2048 * 128 * 2);
    short* v_t   = (short*)alloc((size_t)2 * 128 * 2048 * 2);
    short* attn_bf = x_bf;  // x_bf dead after GEMM1; alias to save workspace
    (void)in_sizes; (void)n_in; (void)out_size; (void)ws_size;

    cvt_f32_bf16<<<1024, 256, 0, stream>>>(x, x_bf, 4096 * 2048);
    cvt_f32_bf16<<<512, 256, 0, stream>>>(wq, wcat, 2048 * 2048);
    cvt_f32_bf16<<<64, 256, 0, stream>>>(wk, wcat + (size_t)2048 * 2048, 128 * 2048);
    cvt_f32_bf16<<<64, 256, 0, stream>>>(wv, wcat + (size_t)2176 * 2048, 128 * 2048);
    cvt_f32_bf16<<<512, 256, 0, stream>>>(wo, wo_bf, 2048 * 2048);

    // qkv = x @ [wq;wk;wv]^T   (M=4096, N=2304, K=2048)
    gemm_bt<<<dim3(18, 32), 256, 0, stream>>>(x_bf, wcat, qkv, 4096, 2304, 2048);

    prep_kernel<<<4096, 256, 0, stream>>>(qkv, cosT, sinT, q_bf, k_bf, v_t);

    attn_kernel<<<dim3(32, 64), 64, 0, stream>>>(q_bf, k_bf, v_t, attn_bf);

    // out = attn @ wo^T   (M=4096, N=2048, K=2048)
    gemm_bt<<<dim3(16, 32), 256, 0, stream>>>(attn_bf, wo_bf, out, 4096, 2048, 2048);
}